// Round 1
// 311.001 us; speedup vs baseline: 1.1199x; 1.1199x over previous
//
#include <hip/hip_runtime.h>
#include <hip/hip_bf16.h>
#include <stdint.h>

typedef __attribute__((ext_vector_type(8)))  __bf16 bf16x8;
typedef __attribute__((ext_vector_type(4)))  float  f32x4;

#define KP 4224   // padded K: 4096 (quantized x) + 32 (lora T) + 96 (zero pad) = 66 tiles of 64

__device__ inline void async_copy16(const void* g, void* l) {
  __builtin_amdgcn_global_load_lds((const __attribute__((address_space(1))) void*)g,
                                   (__attribute__((address_space(3))) void*)l, 16, 0, 0);
}

// ---------------------------------------------------------------------------
// Kernel 1 (FUSED, verified r5, unchanged math): per-block window = rows
// [16*bx,16*bx+16) x cols [1024*by,1024*by+1024).  Part A: SmoothQuant +
// NVFP4 fake-quant -> bf16 into A_big (exact reference fp32 math).  Part B:
// LoRA partial T via MFMA 16x16x32 -> fp32 partial Tp[by][4096][32].
// ---------------------------------------------------------------------------
__global__ __launch_bounds__(256) void fused_quant_lora_kernel(
    const float* __restrict__ x, const float* __restrict__ ss,
    const float* __restrict__ la, __bf16* __restrict__ Ab,
    float* __restrict__ Tp) {
  __shared__ float red[4][16][32];
  int tid  = threadIdx.x;
  int m0   = blockIdx.x << 4;                 // 16-row strip
  int by   = blockIdx.y;                      // 1024-col k-chunk

  // ---- Part A: quant.  thread t -> row m0+(t>>4), col-blocks (t&15)+16i ----
  {
    int row = m0 + (tid >> 4);
    int cb0 = tid & 15;
#pragma unroll
    for (int i = 0; i < 4; i++) {
      int col = (by << 10) + ((cb0 + (i << 4)) << 4);
      const float4* xp = (const float4*)(x + ((size_t)row << 12) + col);
      const float4* sp = (const float4*)(ss + col);
      float xs[16];
#pragma unroll
      for (int j = 0; j < 4; j++) {
        float4 xv = xp[j]; float4 sv = sp[j];
        xs[4*j+0] = xv.x * sv.x; xs[4*j+1] = xv.y * sv.y;
        xs[4*j+2] = xv.z * sv.z; xs[4*j+3] = xv.w * sv.w;
      }
      float amax = 0.f;
#pragma unroll
      for (int j = 0; j < 16; j++) amax = fmaxf(amax, fabsf(xs[j]));
      amax = fmaxf(amax, 1e-12f);
      float scale = amax / 6.0f;              // IEEE fp32 divide, same as np
      bf16x8 o0, o1;
#pragma unroll
      for (int j = 0; j < 16; j++) {
        float a  = fabsf(xs[j]);
        float xn = a / scale;                 // IEEE fp32 divide, same as np
        float bestd = xn;                     // |xn - 0.0|
        float lvl   = 0.f;
        const float L[7] = {0.5f, 1.f, 1.5f, 2.f, 3.f, 4.f, 6.f};
#pragma unroll
        for (int l = 0; l < 7; l++) {         // strict < = first-on-tie (np)
          float d = fabsf(xn - L[l]);
          if (d < bestd) { bestd = d; lvl = L[l]; }
        }
        float mag = lvl * scale;
        float q = (xs[j] > 0.f) ? mag : ((xs[j] < 0.f) ? -mag : 0.f);
        if (j < 8) o0[j] = (__bf16)q; else o1[j-8] = (__bf16)q;
      }
      __bf16* dst = Ab + (size_t)row * KP + col;
      *(bf16x8*)dst = o0;
      *(bf16x8*)(dst + 8) = o1;
    }
  }

  // ---- Part B: LoRA partial via MFMA (verified fragment layout) ----
  {
    int wave = tid >> 6, lane = tid & 63;
    int lrow = lane & 15, kg = lane >> 4;
    int kbase = (by << 10) + (wave << 8);     // 256-wide window per wave
    f32x4 acc0 = {0.f,0.f,0.f,0.f}, acc1 = {0.f,0.f,0.f,0.f};
    const float* xrow = x + ((size_t)(m0 + lrow) << 12);
    const float* a0   = la + ((size_t)lrow << 12);
    const float* a1   = a0 + (16 << 12);
#pragma unroll
    for (int k0 = 0; k0 < 256; k0 += 32) {
      int kk = kbase + k0 + (kg << 3);
      float xv[8], sv[8], v0[8], v1[8];
      *(float4*)&xv[0] = *(const float4*)(xrow + kk);
      *(float4*)&xv[4] = *(const float4*)(xrow + kk + 4);
      *(float4*)&sv[0] = *(const float4*)(ss + kk);
      *(float4*)&sv[4] = *(const float4*)(ss + kk + 4);
      *(float4*)&v0[0] = *(const float4*)(a0 + kk);
      *(float4*)&v0[4] = *(const float4*)(a0 + kk + 4);
      *(float4*)&v1[0] = *(const float4*)(a1 + kk);
      *(float4*)&v1[4] = *(const float4*)(a1 + kk + 4);
      bf16x8 af, b0, b1;
#pragma unroll
      for (int j = 0; j < 8; j++) {
        af[j] = (__bf16)(xv[j] * sv[j]);
        b0[j] = (__bf16)v0[j];
        b1[j] = (__bf16)v1[j];
      }
      acc0 = __builtin_amdgcn_mfma_f32_16x16x32_bf16(af, b0, acc0, 0, 0, 0);
      acc1 = __builtin_amdgcn_mfma_f32_16x16x32_bf16(af, b1, acc1, 0, 0, 0);
    }
#pragma unroll
    for (int r = 0; r < 4; r++) {
      red[wave][kg*4 + r][lrow]      = acc0[r];   // verified layout (r1-r5)
      red[wave][kg*4 + r][16 + lrow] = acc1[r];
    }
    __syncthreads();
    for (int o = tid; o < 512; o += 256) {
      int rr = o >> 5, cc = o & 31;
      float s = red[0][rr][cc] + red[1][rr][cc] + red[2][rr][cc] + red[3][rr][cc];
      Tp[((size_t)by * 4096 + m0 + rr) * 32 + cc] = s;
    }
  }
}

// ---------------------------------------------------------------------------
// Kernel 2 (MERGED wconv + lora_fix): blocks [0,8448) convert w -> bf16 into
// B_big cols 0:4096, lora_b -> 4096:4128, zeros -> 4128:4224.  Blocks
// [8448,8960) sum the 4 Tp partials -> bf16 T into A_big[:,4096:4128] + zero
// pad 4128:4224.  Tp lives in d_out, consumed here before gemm overwrites.
// ---------------------------------------------------------------------------
__global__ __launch_bounds__(256) void wconv_fix_kernel(const float* __restrict__ w,
                                                        const float* __restrict__ lb,
                                                        const float* __restrict__ Tp,
                                                        __bf16* __restrict__ Bb,
                                                        __bf16* __restrict__ Ab) {
  int b = blockIdx.x;
  if (b < 8448) {
    int id  = b * 256 + threadIdx.x;          // < 4096*528
    int row = id / 528;
    int g   = id - row * 528;
    bf16x8 v;
    if (g < 512) {
      const float4* wp = (const float4*)(w + ((size_t)row << 12) + (g << 3));
      float4 a = wp[0], bb = wp[1];
      v[0]=(__bf16)a.x;  v[1]=(__bf16)a.y;  v[2]=(__bf16)a.z;  v[3]=(__bf16)a.w;
      v[4]=(__bf16)bb.x; v[5]=(__bf16)bb.y; v[6]=(__bf16)bb.z; v[7]=(__bf16)bb.w;
    } else if (g < 516) {
      const float* p = lb + (size_t)row * 32 + ((g - 512) << 3);
#pragma unroll
      for (int j = 0; j < 8; j++) v[j] = (__bf16)p[j];
    } else {
#pragma unroll
      for (int j = 0; j < 8; j++) v[j] = (__bf16)0.f;
    }
    *(bf16x8*)(Bb + (size_t)row * KP + ((size_t)g << 3)) = v;
  } else {
    int id  = (b - 8448) * 256 + threadIdx.x; // < 4096*32
    int row = id >> 5, cc = id & 31;
    float s = 0.f;
#pragma unroll
    for (int kc = 0; kc < 4; kc++)
      s += Tp[((size_t)kc * 4096 + row) * 32 + cc];
    __bf16* dst = Ab + (size_t)row * KP + 4096;
    dst[cc]      = (__bf16)s;
    dst[32 + cc] = (__bf16)0.f;
    dst[64 + cc] = (__bf16)0.f;
    dst[96 + cc] = (__bf16)0.f;
  }
}

// ---------------------------------------------------------------------------
// Kernel 3: 256x256-tile 8-phase pipelined GEMM (m201/HK structure, plain
// HIP).  C[4096,4096] = A_big @ B_big^T + bias.
//   - 8 waves (2M x 4N), 512 thr, per-wave output 128x64 = 8x4 frags 16x16.
//   - LDS 128 KiB: 2 dbuf x (A 32K + B 32K), st_16x32 layout: element (r,k)
//     at ((r>>4)*2+(k>>5))*1024 + [(r&15)*64+(k&31)*2] ^ ((r&8)?32:0).
//     Read side: 64-lane ds_read_b128 spreads exactly 8 lanes/bank (even ->
//     conflict-free).  Write side: global_load_lds writes LINEAR; the
//     swizzle is applied by permuting each thread's GLOBAL source address
//     (rule #21: inverse-swz source + swz read).
//   - Per iteration: 2 K-tiles, 8 phases {ds_reads; 1 half-tile stage;
//     s_barrier; MFMA x16 (setprio 1); s_barrier}.  Raw s_barrier only --
//     __syncthreads would drain vmcnt and kill the pipeline.
//   - Counted gates: vmcnt(4) at end of p3 (buf1.A from p0/p1 landed,
//     p2/p3 stages may fly) and end of p7 (buf0 = next even tile complete,
//     p6/p7 fly).  Epilogue iteration stages only t65.A, gates vmcnt(0).
// ---------------------------------------------------------------------------
#define GBAR() __builtin_amdgcn_s_barrier()
#define PRI1() __builtin_amdgcn_s_setprio(1)
#define PRI0() __builtin_amdgcn_s_setprio(0)
#define WVM(n) asm volatile("s_waitcnt vmcnt(" #n ")" ::: "memory")

// stage one half-tile (128 rows x 64 k) of matrix src into buf bb, half h.
// 2 loads/thread; this thread covers row rr (+h*128), k = kk and kk+32.
#define STG(srcb, dstb, bb, h, t) do {                                         \
    const __bf16* _s = (srcb) + (size_t)(h) * (128 * (size_t)KP)               \
                              + ((size_t)(t) << 6);                            \
    char* _d = (dstb) + ((bb) << 15) + ((h) << 14);                            \
    async_copy16(_s, _d);                                                      \
    async_copy16(_s + 32, _d + 1024);                                          \
  } while (0)

#define RDA(p, MFB) do { _Pragma("unroll")                                     \
  for (int u = 0; u < 8; u++)                                                  \
    Afr[u] = *(const bf16x8*)((p) + ((((MFB)*2) + u) << 10)); } while (0)

#define RDB(p, NFB) do { _Pragma("unroll")                                     \
  for (int u = 0; u < 4; u++)                                                  \
    Bfr[(NFB)*2 + u] = *(const bf16x8*)((p) + ((((NFB)*2) + u) << 10)); } while (0)

#define MM(MFB, NFB) do {                                                      \
  _Pragma("unroll") for (int mf = 0; mf < 4; mf++)                             \
  _Pragma("unroll") for (int nf = 0; nf < 2; nf++)                             \
  _Pragma("unroll") for (int ks = 0; ks < 2; ks++)                             \
    acc[(MFB)+mf][(NFB)+nf] = __builtin_amdgcn_mfma_f32_16x16x32_bf16(         \
        Afr[mf*2+ks], Bfr[((NFB)+nf)*2+ks], acc[(MFB)+mf][(NFB)+nf], 0, 0, 0); \
  } while (0)

__global__ __launch_bounds__(512, 2) void gemm_kernel(const __bf16* __restrict__ A,
                                                      const __bf16* __restrict__ B,
                                                      const float* __restrict__ bias,
                                                      float* __restrict__ C) {
  extern __shared__ char lds[];                // 131072 B: [A0|A1|B0|B1] 32K each
  const int tid  = threadIdx.x;
  const int w    = tid >> 6, lane = tid & 63;
  const int ln15 = lane & 15, kg = lane >> 4;
  const int wm   = w >> 2, wn = w & 3;
  const int bid  = blockIdx.x;
  const int sbid = ((bid & 7) << 5) | (bid >> 3);  // XCD swizzle (256%8==0, bijective)
  const int bm   = sbid >> 4, bn = sbid & 15;
  const size_t m0 = (size_t)bm << 8, n0 = (size_t)bn << 8;

  // staging source (per-thread, inverse-swizzled): chunk C=w*128+i*64+lane
  // decodes to row rr = w*16 + lane/4 (+h*128), k = kk + i*32.
  const int rr = (w << 4) + (lane >> 2);
  const int kk = ((lane & 3) ^ (((lane >> 5) & 1) << 1)) << 3;
  const __bf16* aS = A + (m0 + rr) * (size_t)KP + kk;
  const __bf16* bS = B + (n0 + rr) * (size_t)KP + kk;
  char* dA = lds + (w << 11);                  // wave-uniform LDS dest bases
  char* dB = lds + 65536 + (w << 11);

  // fragment read pointers (swizzled): row ln15 of subtile, k-bytes kg*16
  int inner = (ln15 << 6) + (kg << 4);
  inner ^= (ln15 & 8) << 2;                    // ^32 when row&8
  const char* pA0 = lds + (wm << 14) + inner;
  const char* pA1 = pA0 + 32768;
  const char* pB0 = lds + 65536 + (wn << 13) + inner;
  const char* pB1 = pB0 + 32768;

  bf16x8 Afr[8], Bfr[8];
  f32x4 acc[8][4];
#pragma unroll
  for (int i = 0; i < 8; i++)
#pragma unroll
    for (int j = 0; j < 4; j++) acc[i][j] = (f32x4){0.f, 0.f, 0.f, 0.f};

  // prologue: tile0 -> buf0 (B then A halves), tile1.B -> buf1.
  // vmcnt(4): tile0's 8 loads landed, tile1.B's 4 may fly.
  STG(bS, dB, 0, 0, 0); STG(bS, dB, 0, 1, 0);
  STG(aS, dA, 0, 0, 0); STG(aS, dA, 0, 1, 0);
  STG(bS, dB, 1, 0, 1); STG(bS, dB, 1, 1, 1);
  WVM(4);
  GBAR();

#pragma unroll 1
  for (int i = 0; i < 32; i++) {
    const int t1 = 2*i + 1, t2 = 2*i + 2, t3 = 2*i + 3;
    // ---- tile 2i (buf0) ----
    // p0: A m0-3 + B n0-1 reads; stage buf1.A h0 (t1)
    RDA(pA0, 0); RDB(pB0, 0); STG(aS, dA, 1, 0, t1);
    GBAR(); PRI1(); MM(0, 0); PRI0(); GBAR();
    // p1: B n2-3 reads; stage buf1.A h1 (t1)
    RDB(pB0, 2); STG(aS, dA, 1, 1, t1);
    GBAR(); PRI1(); MM(0, 2); PRI0(); GBAR();
    // p2: A m4-7 reads; stage buf0.B h0 (t2) [buf0.B last read at p1]
    RDA(pA0, 4); STG(bS, dB, 0, 0, t2);
    GBAR(); PRI1(); MM(4, 0); PRI0(); GBAR();
    // p3: no reads; stage buf0.B h1 (t2); GATE: buf1 complete for p4
    STG(bS, dB, 0, 1, t2);
    GBAR(); PRI1(); MM(4, 2); PRI0(); WVM(4); GBAR();
    // ---- tile 2i+1 (buf1) ----
    // p4: stage buf0.A h0 (t2) [buf0.A last read at p2]
    RDA(pA1, 0); RDB(pB1, 0); STG(aS, dA, 0, 0, t2);
    GBAR(); PRI1(); MM(0, 0); PRI0(); GBAR();
    // p5: stage buf0.A h1 (t2)
    RDB(pB1, 2); STG(aS, dA, 0, 1, t2);
    GBAR(); PRI1(); MM(0, 2); PRI0(); GBAR();
    // p6: stage buf1.B h0 (t3) [buf1.B last read at p5]
    RDA(pA1, 4); STG(bS, dB, 1, 0, t3);
    GBAR(); PRI1(); MM(4, 0); PRI0(); GBAR();
    // p7: stage buf1.B h1 (t3); GATE: buf0 (t2) complete for next p0
    STG(bS, dB, 1, 1, t3);
    GBAR(); PRI1(); MM(4, 2); PRI0(); WVM(4); GBAR();
  }

  // epilogue iteration: tiles 64 (buf0) and 65 (buf1); only t65.A stages.
  RDA(pA0, 0); RDB(pB0, 0); STG(aS, dA, 1, 0, 65);
  GBAR(); PRI1(); MM(0, 0); PRI0(); GBAR();
  RDB(pB0, 2); STG(aS, dA, 1, 1, 65);
  GBAR(); PRI1(); MM(0, 2); PRI0(); GBAR();
  RDA(pA0, 4);
  GBAR(); PRI1(); MM(4, 0); PRI0(); GBAR();
  GBAR(); PRI1(); MM(4, 2); PRI0(); WVM(0); GBAR();
  RDA(pA1, 0); RDB(pB1, 0);
  GBAR(); PRI1(); MM(0, 0); PRI0(); GBAR();
  RDB(pB1, 2);
  GBAR(); PRI1(); MM(0, 2); PRI0(); GBAR();
  RDA(pA1, 4);
  GBAR(); PRI1(); MM(4, 0); PRI0(); GBAR();
  GBAR(); PRI1(); MM(4, 2); PRI0(); GBAR();

  // epilogue: + bias, fp32 store.  C/D layout: col=lane&15, row=(lane>>4)*4+q.
  const int    colb = (int)n0 + (wn << 6) + ln15;
  const size_t rowb = m0 + ((size_t)wm << 7) + (kg << 2);
#pragma unroll
  for (int nf = 0; nf < 4; nf++) {
    const int col = colb + (nf << 4);
    const float bv = bias[col];
#pragma unroll
    for (int mf = 0; mf < 8; mf++) {
      const size_t r0 = rowb + ((size_t)mf << 4);
#pragma unroll
      for (int q = 0; q < 4; q++)
        C[(r0 + q) * 4096 + col] = acc[mf][nf][q] + bv;
    }
  }
}

extern "C" void kernel_launch(void* const* d_in, const int* in_sizes, int n_in,
                              void* d_out, int out_size, void* d_ws, size_t ws_size,
                              hipStream_t stream) {
  const float* x    = (const float*)d_in[0];   // [2,2048,4096]
  const float* ss   = (const float*)d_in[1];   // [4096]
  const float* w    = (const float*)d_in[2];   // [4096,4096]
  const float* la   = (const float*)d_in[3];   // [32,4096]
  const float* lb   = (const float*)d_in[4];   // [4096,32]
  const float* bias = (const float*)d_in[5];   // [4096]
  float* out = (float*)d_out;                  // [2,2048,4096] fp32

  __bf16* Ab = (__bf16*)d_ws;                  // [4096, 4224] bf16  (34.6 MB)
  __bf16* Bb = Ab + (size_t)4096 * KP;         // [4096, 4224] bf16  (34.6 MB)
  // Tp lives in d_out scratch space: 4*4096*32*4 = 2 MB << 67 MB.  Consumed
  // by wconv_fix, then d_out fully overwritten by gemm.
  float* Tp = out;                             // [4][4096][32] fp32 (2 MB)

  static bool s_attr = false;
  if (!s_attr) {                               // config call, not a stream op
    hipFuncSetAttribute((const void*)gemm_kernel,
                        hipFuncAttributeMaxDynamicSharedMemorySize, 131072);
    s_attr = true;
  }

  fused_quant_lora_kernel<<<dim3(256, 4), 256, 0, stream>>>(x, ss, la, Ab, Tp);
  wconv_fix_kernel<<<8960, 256, 0, stream>>>(w, lb, Tp, Bb, Ab);
  gemm_kernel<<<256, 512, 131072, stream>>>(Ab, Bb, bias, out);
}

// Round 3
// 310.081 us; speedup vs baseline: 1.1233x; 1.0030x over previous
//
#include <hip/hip_runtime.h>
#include <hip/hip_bf16.h>
#include <stdint.h>

typedef __attribute__((ext_vector_type(8)))  __bf16 bf16x8;
typedef __attribute__((ext_vector_type(4)))  float  f32x4;

#define KP 4224   // padded K: 4096 (quantized x) + 32 (lora T) + 96 (zero pad) = 66 tiles of 64

__device__ inline void async_copy16(const void* g, void* l) {
  __builtin_amdgcn_global_load_lds((const __attribute__((address_space(1))) void*)g,
                                   (__attribute__((address_space(3))) void*)l, 16, 0, 0);
}

// ---------------------------------------------------------------------------
// Kernel 1 (FUSED): per-block window = rows [16*bx,+16) x cols [512*by,+512).
// Grid (256,8) -> 8 blocks/CU (2x the waves of r1 for latency hiding).
// Part A: SmoothQuant + NVFP4 fake-quant -> bf16 into A_big.  Level select is
// CLOSED-FORM, bit-exact vs the reference argmin (proof: for xn<2.25 levels
// are the 0.5-grid; 2*xn-0.5 is exactly representable so ceil() reproduces
// nearest-with-tie-down == argmin-first; else midpoints 2.5/3.5/5.0 with <=
// give tie-down).  Part B: LoRA partial T via MFMA -> Tp[by][4096][32].
// ---------------------------------------------------------------------------
__global__ __launch_bounds__(256) void fused_quant_lora_kernel(
    const float* __restrict__ x, const float* __restrict__ ss,
    const float* __restrict__ la, __bf16* __restrict__ Ab,
    float* __restrict__ Tp) {
  __shared__ float red[4][16][32];
  int tid  = threadIdx.x;
  int m0   = blockIdx.x << 4;                 // 16-row strip
  int by   = blockIdx.y;                      // 512-col k-chunk

  // ---- Part A: quant.  thread t -> row m0+(t>>4), col-blocks (t&15)+16i ----
  {
    int row = m0 + (tid >> 4);
    int cb0 = tid & 15;
#pragma unroll
    for (int i = 0; i < 2; i++) {
      int col = (by << 9) + ((cb0 + (i << 4)) << 4);
      const float4* xp = (const float4*)(x + ((size_t)row << 12) + col);
      const float4* sp = (const float4*)(ss + col);
      float xs[16];
#pragma unroll
      for (int j = 0; j < 4; j++) {
        float4 xv = xp[j]; float4 sv = sp[j];
        xs[4*j+0] = xv.x * sv.x; xs[4*j+1] = xv.y * sv.y;
        xs[4*j+2] = xv.z * sv.z; xs[4*j+3] = xv.w * sv.w;
      }
      float amax = 0.f;
#pragma unroll
      for (int j = 0; j < 16; j++) amax = fmaxf(amax, fabsf(xs[j]));
      amax = fmaxf(amax, 1e-12f);
      float scale = amax / 6.0f;              // IEEE fp32 divide, same as np
      bf16x8 o0, o1;
#pragma unroll
      for (int j = 0; j < 16; j++) {
        float a  = fabsf(xs[j]);
        float xn = a / scale;                 // IEEE fp32 divide, same as np
        float lvl;
        if (xn < 2.25f) {
          // 0.5-grid nearest, tie -> lower (== argmin first-on-tie)
          lvl = 0.5f * __builtin_ceilf(__builtin_fmaf(2.0f, xn, -0.5f));
        } else {
          lvl = (xn <= 2.5f) ? 2.0f : (xn <= 3.5f) ? 3.0f
              : (xn <= 5.0f) ? 4.0f : 6.0f;
        }
        float mag = lvl * scale;
        float q = (xs[j] > 0.f) ? mag : ((xs[j] < 0.f) ? -mag : 0.f);
        if (j < 8) o0[j] = (__bf16)q; else o1[j-8] = (__bf16)q;
      }
      __bf16* dst = Ab + (size_t)row * KP + col;
      *(bf16x8*)dst = o0;
      *(bf16x8*)(dst + 8) = o1;
    }
  }

  // ---- Part B: LoRA partial via MFMA (verified fragment layout) ----
  {
    int wave = tid >> 6, lane = tid & 63;
    int lrow = lane & 15, kg = lane >> 4;
    int kbase = (by << 9) + (wave << 7);      // 128-wide window per wave
    f32x4 acc0 = {0.f,0.f,0.f,0.f}, acc1 = {0.f,0.f,0.f,0.f};
    const float* xrow = x + ((size_t)(m0 + lrow) << 12);
    const float* a0   = la + ((size_t)lrow << 12);
    const float* a1   = a0 + (16 << 12);
#pragma unroll
    for (int k0 = 0; k0 < 128; k0 += 32) {
      int kk = kbase + k0 + (kg << 3);
      float xv[8], sv[8], v0[8], v1[8];
      *(float4*)&xv[0] = *(const float4*)(xrow + kk);
      *(float4*)&xv[4] = *(const float4*)(xrow + kk + 4);
      *(float4*)&sv[0] = *(const float4*)(ss + kk);
      *(float4*)&sv[4] = *(const float4*)(ss + kk + 4);
      *(float4*)&v0[0] = *(const float4*)(a0 + kk);
      *(float4*)&v0[4] = *(const float4*)(a0 + kk + 4);
      *(float4*)&v1[0] = *(const float4*)(a1 + kk);
      *(float4*)&v1[4] = *(const float4*)(a1 + kk + 4);
      bf16x8 af, b0, b1;
#pragma unroll
      for (int j = 0; j < 8; j++) {
        af[j] = (__bf16)(xv[j] * sv[j]);
        b0[j] = (__bf16)v0[j];
        b1[j] = (__bf16)v1[j];
      }
      acc0 = __builtin_amdgcn_mfma_f32_16x16x32_bf16(af, b0, acc0, 0, 0, 0);
      acc1 = __builtin_amdgcn_mfma_f32_16x16x32_bf16(af, b1, acc1, 0, 0, 0);
    }
#pragma unroll
    for (int r = 0; r < 4; r++) {
      red[wave][kg*4 + r][lrow]      = acc0[r];   // verified layout (r1-r5)
      red[wave][kg*4 + r][16 + lrow] = acc1[r];
    }
    __syncthreads();
    for (int o = tid; o < 512; o += 256) {
      int rr = o >> 5, cc = o & 31;
      float s = red[0][rr][cc] + red[1][rr][cc] + red[2][rr][cc] + red[3][rr][cc];
      Tp[((size_t)by * 4096 + m0 + rr) * 32 + cc] = s;
    }
  }
}

// ---------------------------------------------------------------------------
// Kernel 2 (MERGED wconv + lora_fix): blocks [0,8448) convert w -> bf16 into
// B_big cols 0:4096, lora_b -> 4096:4128, zeros -> 4128:4224.  Blocks
// [8448,8960) sum the 8 Tp partials -> bf16 T into A_big[:,4096:4128] + pad.
// ---------------------------------------------------------------------------
__global__ __launch_bounds__(256) void wconv_fix_kernel(const float* __restrict__ w,
                                                        const float* __restrict__ lb,
                                                        const float* __restrict__ Tp,
                                                        __bf16* __restrict__ Bb,
                                                        __bf16* __restrict__ Ab) {
  int b = blockIdx.x;
  if (b < 8448) {
    int id  = b * 256 + threadIdx.x;          // < 4096*528
    int row = id / 528;
    int g   = id - row * 528;
    bf16x8 v;
    if (g < 512) {
      const float4* wp = (const float4*)(w + ((size_t)row << 12) + (g << 3));
      float4 a = wp[0], bb = wp[1];
      v[0]=(__bf16)a.x;  v[1]=(__bf16)a.y;  v[2]=(__bf16)a.z;  v[3]=(__bf16)a.w;
      v[4]=(__bf16)bb.x; v[5]=(__bf16)bb.y; v[6]=(__bf16)bb.z; v[7]=(__bf16)bb.w;
    } else if (g < 516) {
      const float* p = lb + (size_t)row * 32 + ((g - 512) << 3);
#pragma unroll
      for (int j = 0; j < 8; j++) v[j] = (__bf16)p[j];
    } else {
#pragma unroll
      for (int j = 0; j < 8; j++) v[j] = (__bf16)0.f;
    }
    *(bf16x8*)(Bb + (size_t)row * KP + ((size_t)g << 3)) = v;
  } else {
    int id  = (b - 8448) * 256 + threadIdx.x; // < 4096*32
    int row = id >> 5, cc = id & 31;
    float s = 0.f;
#pragma unroll
    for (int kc = 0; kc < 8; kc++)
      s += Tp[((size_t)kc * 4096 + row) * 32 + cc];
    __bf16* dst = Ab + (size_t)row * KP + 4096;
    dst[cc]      = (__bf16)s;
    dst[32 + cc] = (__bf16)0.f;
    dst[64 + cc] = (__bf16)0.f;
    dst[96 + cc] = (__bf16)0.f;
  }
}

// ---------------------------------------------------------------------------
// Kernel 3: 256x256 8-phase GEMM, now with REGISTER-double-buffered frags.
// Each phase: [s_barrier] stage-issue; prefetch next phase's ds_reads; MFMA
// (prio 1) on frags issued >=1 phase earlier.  ds_read latency hides under
// MFMA; ONE barrier per phase (16->8/iter).  Gates move to p2/p6 end:
// WVM(2) proves the buffer needed by the NEXT phase's prefetch has landed
// (issued-since-last-gate = 6 resp. 8 loads; keeping 2 newest in flight
// leaves exactly the not-yet-needed stage pair).  Cross-wave visibility:
// prefetches are issued AFTER the barrier that follows the gate.
// WAR safety (single barrier): every stage overwrites a region whose LDS
// reads completed >=2 barriers earlier (A-halves: read p4-p7 prev iter via
// regs loaded p3/p4, restaged p0/p1; B-halves: reads complete by p1's lgkm
// wait, restaged p2/p3).
// ---------------------------------------------------------------------------
#define GBAR() __builtin_amdgcn_s_barrier()
#define PRI1() __builtin_amdgcn_s_setprio(1)
#define PRI0() __builtin_amdgcn_s_setprio(0)
#define WVM(n) asm volatile("s_waitcnt vmcnt(" #n ")" ::: "memory")

#define STG(srcb, dstb, bb, h, t) do {                                         \
    const __bf16* _s = (srcb) + (size_t)(h) * (128 * (size_t)KP)               \
                              + ((size_t)(t) << 6);                            \
    char* _d = (dstb) + ((bb) << 15) + ((h) << 14);                            \
    async_copy16(_s, _d);                                                      \
    async_copy16(_s + 32, _d + 1024);                                          \
  } while (0)

#define LD8(dst, p, off) do { _Pragma("unroll")                                \
  for (int u = 0; u < 8; u++)                                                  \
    dst[u] = *(const bf16x8*)((p) + (((off) + u) << 10)); } while (0)

#define LD4(dst, p, off) do { _Pragma("unroll")                                \
  for (int u = 0; u < 4; u++)                                                  \
    dst[u] = *(const bf16x8*)((p) + (((off) + u) << 10)); } while (0)

#define MMQ(Ar, Br, MFB, NFB) do {                                             \
  _Pragma("unroll") for (int mf = 0; mf < 4; mf++)                             \
  _Pragma("unroll") for (int nf = 0; nf < 2; nf++)                             \
  _Pragma("unroll") for (int ks = 0; ks < 2; ks++)                             \
    acc[(MFB)+mf][(NFB)+nf] = __builtin_amdgcn_mfma_f32_16x16x32_bf16(         \
        Ar[mf*2+ks], Br[nf*2+ks], acc[(MFB)+mf][(NFB)+nf], 0, 0, 0);           \
  } while (0)

__global__ __launch_bounds__(512, 2) void gemm_kernel(const __bf16* __restrict__ A,
                                                      const __bf16* __restrict__ B,
                                                      const float* __restrict__ bias,
                                                      float* __restrict__ C) {
  extern __shared__ char lds[];                // 131072 B: [A0|A1|B0|B1] 32K each
  const int tid  = threadIdx.x;
  const int w    = tid >> 6, lane = tid & 63;
  const int ln15 = lane & 15, kg = lane >> 4;
  const int wm   = w >> 2, wn = w & 3;
  const int bid  = blockIdx.x;
  const int sbid = ((bid & 7) << 5) | (bid >> 3);  // XCD swizzle (256%8==0, bijective)
  const int bm   = sbid >> 4, bn = sbid & 15;
  const size_t m0 = (size_t)bm << 8, n0 = (size_t)bn << 8;

  // staging source (per-thread, inverse-swizzled)
  const int rr = (w << 4) + (lane >> 2);
  const int kk = ((lane & 3) ^ (((lane >> 5) & 1) << 1)) << 3;
  const __bf16* aS = A + (m0 + rr) * (size_t)KP + kk;
  const __bf16* bS = B + (n0 + rr) * (size_t)KP + kk;
  char* dA = lds + (w << 11);                  // wave-uniform LDS dest bases
  char* dB = lds + 65536 + (w << 11);

  // fragment read pointers (swizzled)
  int inner = (ln15 << 6) + (kg << 4);
  inner ^= (ln15 & 8) << 2;                    // ^32 when row&8
  const char* pA0 = lds + (wm << 14) + inner;
  const char* pA1 = pA0 + 32768;
  const char* pB0 = lds + 65536 + (wn << 13) + inner;
  const char* pB1 = pB0 + 32768;

  bf16x8 Ax[8], Ay[8], Bg0[4], Bg1[4];
  f32x4 acc[8][4];
#pragma unroll
  for (int i = 0; i < 8; i++)
#pragma unroll
    for (int j = 0; j < 4; j++) acc[i][j] = (f32x4){0.f, 0.f, 0.f, 0.f};

  // prologue: tile0 -> buf0, tile1.B -> buf1; then preload first frags.
  STG(bS, dB, 0, 0, 0); STG(bS, dB, 0, 1, 0);
  STG(aS, dA, 0, 0, 0); STG(aS, dA, 0, 1, 0);
  STG(bS, dB, 1, 0, 1); STG(bS, dB, 1, 1, 1);
  WVM(4);
  GBAR();
  LD8(Ax, pA0, 0); LD4(Bg0, pB0, 0);

#pragma unroll 1
  for (int i = 0; i < 32; i++) {
    const int t1 = 2*i + 1, t2 = 2*i + 2, t3 = 2*i + 3;
    // ---- tile 2i (buf0) ----
    GBAR();                                    // p0
    STG(aS, dA, 1, 0, t1);
    LD8(Ay, pA0, 8); LD4(Bg1, pB0, 4);
    PRI1(); MMQ(Ax, Bg0, 0, 0); PRI0();
    GBAR();                                    // p1
    STG(aS, dA, 1, 1, t1);
    PRI1(); MMQ(Ax, Bg1, 0, 2); PRI0();
    GBAR();                                    // p2
    STG(bS, dB, 0, 0, t2);
    PRI1(); MMQ(Ay, Bg0, 4, 0); PRI0();
    WVM(2);                                    // gate: buf1 (t1.A + t1.B) landed
    GBAR();                                    // p3
    STG(bS, dB, 0, 1, t2);
    LD8(Ax, pA1, 0); LD4(Bg0, pB1, 0);
    PRI1(); MMQ(Ay, Bg1, 4, 2); PRI0();
    // ---- tile 2i+1 (buf1) ----
    GBAR();                                    // p4
    STG(aS, dA, 0, 0, t2);
    LD8(Ay, pA1, 8); LD4(Bg1, pB1, 4);
    PRI1(); MMQ(Ax, Bg0, 0, 0); PRI0();
    GBAR();                                    // p5
    STG(aS, dA, 0, 1, t2);
    PRI1(); MMQ(Ax, Bg1, 0, 2); PRI0();
    GBAR();                                    // p6
    STG(bS, dB, 1, 0, t3);
    PRI1(); MMQ(Ay, Bg0, 4, 0); PRI0();
    WVM(2);                                    // gate: buf0 (t2) landed
    GBAR();                                    // p7
    STG(bS, dB, 1, 1, t3);
    LD8(Ax, pA0, 0); LD4(Bg0, pB0, 0);
    PRI1(); MMQ(Ay, Bg1, 4, 2); PRI0();
  }

  // epilogue: tiles 64 (buf0) and 65 (buf1); only t65.A still needs staging.
  GBAR();                                      // e0
  STG(aS, dA, 1, 0, 65);
  LD8(Ay, pA0, 8); LD4(Bg1, pB0, 4);
  PRI1(); MMQ(Ax, Bg0, 0, 0); PRI0();
  GBAR();                                      // e1
  STG(aS, dA, 1, 1, 65);
  PRI1(); MMQ(Ax, Bg1, 0, 2); PRI0();
  GBAR();                                      // e2
  PRI1(); MMQ(Ay, Bg0, 4, 0); PRI0();
  WVM(0);                                      // gate: t65.A + t65.B landed
  GBAR();                                      // e3
  LD8(Ax, pA1, 0); LD4(Bg0, pB1, 0);
  PRI1(); MMQ(Ay, Bg1, 4, 2); PRI0();
  GBAR();                                      // e4
  LD8(Ay, pA1, 8); LD4(Bg1, pB1, 4);
  PRI1(); MMQ(Ax, Bg0, 0, 0); PRI0();
  GBAR();                                      // e5
  PRI1(); MMQ(Ax, Bg1, 0, 2); PRI0();
  GBAR();                                      // e6
  PRI1(); MMQ(Ay, Bg0, 4, 0); PRI0();
  GBAR();                                      // e7
  PRI1(); MMQ(Ay, Bg1, 4, 2); PRI0();

  // epilogue: + bias, fp32 store.  C/D layout: col=lane&15, row=(lane>>4)*4+q.
  const int    colb = (int)n0 + (wn << 6) + ln15;
  const size_t rowb = m0 + ((size_t)wm << 7) + (kg << 2);
#pragma unroll
  for (int nf = 0; nf < 4; nf++) {
    const int col = colb + (nf << 4);
    const float bv = bias[col];
#pragma unroll
    for (int mf = 0; mf < 8; mf++) {
      const size_t r0 = rowb + ((size_t)mf << 4);
#pragma unroll
      for (int q = 0; q < 4; q++)
        C[(r0 + q) * 4096 + col] = acc[mf][nf][q] + bv;
    }
  }
}

extern "C" void kernel_launch(void* const* d_in, const int* in_sizes, int n_in,
                              void* d_out, int out_size, void* d_ws, size_t ws_size,
                              hipStream_t stream) {
  const float* x    = (const float*)d_in[0];   // [2,2048,4096]
  const float* ss   = (const float*)d_in[1];   // [4096]
  const float* w    = (const float*)d_in[2];   // [4096,4096]
  const float* la   = (const float*)d_in[3];   // [32,4096]
  const float* lb   = (const float*)d_in[4];   // [4096,32]
  const float* bias = (const float*)d_in[5];   // [4096]
  float* out = (float*)d_out;                  // [2,2048,4096] fp32

  __bf16* Ab = (__bf16*)d_ws;                  // [4096, 4224] bf16  (34.6 MB)
  __bf16* Bb = Ab + (size_t)4096 * KP;         // [4096, 4224] bf16  (34.6 MB)
  // Tp lives in d_out scratch space: 8*4096*32*4 = 4 MB << 67 MB.  Consumed
  // by wconv_fix, then d_out fully overwritten by gemm.
  float* Tp = out;                             // [8][4096][32] fp32 (4 MB)

  static bool s_attr = false;
  if (!s_attr) {                               // config call, not a stream op
    hipFuncSetAttribute((const void*)gemm_kernel,
                        hipFuncAttributeMaxDynamicSharedMemorySize, 131072);
    s_attr = true;
  }

  fused_quant_lora_kernel<<<dim3(256, 8), 256, 0, stream>>>(x, ss, la, Ab, Tp);
  wconv_fix_kernel<<<8960, 256, 0, stream>>>(w, lb, Tp, Bb, Ab);
  gemm_kernel<<<256, 512, 131072, stream>>>(Ab, Bb, bias, out);
}